// Round 1
// baseline (1473.773 us; speedup 1.0000x reference)
//
#include <hip/hip_runtime.h>
#include <hip/hip_bf16.h>
#include <cstdint>

#define N_NODES 100000
#define N_EDGES 1600000

static inline size_t alup(size_t x) { return (x + 255) & ~(size_t)255; }

// ---------------- prep kernels ----------------

__global__ __launch_bounds__(256) void k_deg(const int* __restrict__ ei, int* __restrict__ deg) {
  int e = blockIdx.x * 256 + threadIdx.x;
  if (e < N_EDGES) {
    atomicAdd(&deg[ei[e]], 1);            // out node endpoint
    atomicAdd(&deg[ei[N_EDGES + e]], 1);  // in node endpoint
  }
}

__global__ __launch_bounds__(256) void k_dinv(const int* __restrict__ deg, float* __restrict__ dinv) {
  int i = blockIdx.x * 256 + threadIdx.x;
  if (i < N_NODES) dinv[i] = rsqrtf((float)(deg[i] + 1));  // +1 self loop
}

__global__ __launch_bounds__(1024) void k_scan(const int* __restrict__ deg,
                                               int* __restrict__ rowptr,
                                               int* __restrict__ cursor) {
  __shared__ int part[1024];
  const int CH = (N_NODES + 1023) / 1024;  // 98
  const int t = threadIdx.x;
  const int s0 = t * CH, s1 = min(s0 + CH, N_NODES);
  int s = 0;
  for (int i = s0; i < s1; ++i) s += deg[i];
  part[t] = s;
  __syncthreads();
  for (int off = 1; off < 1024; off <<= 1) {
    int v = (t >= off) ? part[t - off] : 0;
    __syncthreads();
    if (t >= off) part[t] += v;
    __syncthreads();
  }
  int excl = (t == 0) ? 0 : part[t - 1];
  for (int i = s0; i < s1; ++i) {
    rowptr[i] = excl;
    cursor[i] = excl;
    excl += deg[i];
  }
  if (t == 1023) rowptr[N_NODES] = excl;  // = 2*N_EDGES
}

__global__ __launch_bounds__(256) void k_scatter(const int* __restrict__ ei,
                                                 int* __restrict__ cursor,
                                                 int* __restrict__ col) {
  int e = blockIdx.x * 256 + threadIdx.x;
  if (e < 2 * N_EDGES) {
    int s = ei[e];  // src: out_nodes for e<E, in_nodes for e>=E (same index!)
    int d = (e < N_EDGES) ? ei[N_EDGES + e] : ei[e - N_EDGES];
    int pos = atomicAdd(&cursor[d], 1);
    col[pos] = s;
  }
}

// ---------------- GEMM: h = x @ W.T  (fp32) ----------------
// Block computes 32 rows x 64 cols. W-half transposed in LDS (stride 68),
// x tile transposed in LDS (stride 33). 2x4 register micro-tile per thread.
template<int OUT>
__global__ __launch_bounds__(256) void k_gemm(const float* __restrict__ x,
                                              const float* __restrict__ W,
                                              float* __restrict__ h) {
  __shared__ float wlds[128 * 68];
  __shared__ float xlds[128 * 33];
  const int tid = threadIdx.x;
  const int cg = tid & 15;   // 16 col groups x 4 cols
  const int rg = tid >> 4;   // 16 row groups x 2 rows
  const int obase = blockIdx.y * 64;
  // stage W transposed: wlds[k*68 + o] = W[(obase+o)*128 + k]
  for (int idx = tid; idx < 64 * 32; idx += 256) {
    int o = idx >> 5;
    int k4 = (idx & 31) << 2;
    const float4 wv = *(const float4*)(W + (size_t)(obase + o) * 128 + k4);
    wlds[(k4 + 0) * 68 + o] = wv.x;
    wlds[(k4 + 1) * 68 + o] = wv.y;
    wlds[(k4 + 2) * 68 + o] = wv.z;
    wlds[(k4 + 3) * 68 + o] = wv.w;
  }
  for (int tile = blockIdx.x; tile < N_NODES / 32; tile += gridDim.x) {
    const int row0 = tile * 32;
    __syncthreads();  // protect xlds (and order W staging on iter 0)
    for (int idx = tid; idx < 32 * 32; idx += 256) {
      int r = idx >> 5;
      int k4 = (idx & 31) << 2;
      const float4 xv = *(const float4*)(x + (size_t)(row0 + r) * 128 + k4);
      xlds[(k4 + 0) * 33 + r] = xv.x;
      xlds[(k4 + 1) * 33 + r] = xv.y;
      xlds[(k4 + 2) * 33 + r] = xv.z;
      xlds[(k4 + 3) * 33 + r] = xv.w;
    }
    __syncthreads();
    float a00 = 0, a01 = 0, a02 = 0, a03 = 0;
    float a10 = 0, a11 = 0, a12 = 0, a13 = 0;
#pragma unroll 4
    for (int k = 0; k < 128; ++k) {
      const float4 wv = *(const float4*)(wlds + k * 68 + cg * 4);
      const float x0 = xlds[k * 33 + rg * 2 + 0];
      const float x1 = xlds[k * 33 + rg * 2 + 1];
      a00 = fmaf(x0, wv.x, a00); a01 = fmaf(x0, wv.y, a01);
      a02 = fmaf(x0, wv.z, a02); a03 = fmaf(x0, wv.w, a03);
      a10 = fmaf(x1, wv.x, a10); a11 = fmaf(x1, wv.y, a11);
      a12 = fmaf(x1, wv.z, a12); a13 = fmaf(x1, wv.w, a13);
    }
    float* hp = h + (size_t)(row0 + rg * 2) * OUT + obase + cg * 4;
    *(float4*)hp = make_float4(a00, a01, a02, a03);
    *(float4*)(hp + OUT) = make_float4(a10, a11, a12, a13);
  }
}

// ---------------- aggregation: out[i] = di*sum(dinv[c]*h[c]) + di^2*h[i] + b ----------------
// One wave per node. Width 128: lane holds cols {2l, 2l+1} as float2.
template<bool RELU>
__global__ __launch_bounds__(256) void k_agg128(const float* __restrict__ h,
                                                const float* __restrict__ dinv,
                                                const int* __restrict__ rowptr,
                                                const int* __restrict__ col,
                                                const float* __restrict__ bias,
                                                float* __restrict__ out) {
  const int lane = threadIdx.x & 63;
  const int node = blockIdx.x * 4 + (threadIdx.x >> 6);
  if (node >= N_NODES) return;
  const int e0 = rowptr[node], e1 = rowptr[node + 1];
  const float2* hp = (const float2*)h;
  float ax = 0.f, ay = 0.f;
  for (int eb = e0; eb < e1; eb += 64) {
    const int n = min(64, e1 - eb);
    const int ce = col[min(eb + lane, e1 - 1)];
    const float we = dinv[ce];
    for (int j = 0; j < n; ++j) {
      const int c = __shfl(ce, j);
      const float w = __shfl(we, j);
      const float2 v = hp[(size_t)c * 64 + lane];
      ax = fmaf(w, v.x, ax);
      ay = fmaf(w, v.y, ay);
    }
  }
  const float di = dinv[node];
  const float2 hv = hp[(size_t)node * 64 + lane];
  const float2 bv = ((const float2*)bias)[lane];
  float ox = di * ax + di * di * hv.x + bv.x;
  float oy = di * ay + di * di * hv.y + bv.y;
  if (RELU) { ox = fmaxf(ox, 0.f); oy = fmaxf(oy, 0.f); }
  ((float2*)out)[(size_t)node * 64 + lane] = make_float2(ox, oy);
}

// Width 64 + fused bias + log_softmax (final layer). Lane holds col l.
__global__ __launch_bounds__(256) void k_agg64_lsm(const float* __restrict__ h,
                                                   const float* __restrict__ dinv,
                                                   const int* __restrict__ rowptr,
                                                   const int* __restrict__ col,
                                                   const float* __restrict__ bias,
                                                   float* __restrict__ out) {
  const int lane = threadIdx.x & 63;
  const int node = blockIdx.x * 4 + (threadIdx.x >> 6);
  if (node >= N_NODES) return;
  const int e0 = rowptr[node], e1 = rowptr[node + 1];
  float acc = 0.f;
  for (int eb = e0; eb < e1; eb += 64) {
    const int n = min(64, e1 - eb);
    const int ce = col[min(eb + lane, e1 - 1)];
    const float we = dinv[ce];
    for (int j = 0; j < n; ++j) {
      const int c = __shfl(ce, j);
      const float w = __shfl(we, j);
      acc = fmaf(w, h[(size_t)c * 64 + lane], acc);
    }
  }
  const float di = dinv[node];
  float v = di * acc + di * di * h[(size_t)node * 64 + lane] + bias[lane];
  // log_softmax over the 64 lanes
  float m = v;
#pragma unroll
  for (int off = 32; off > 0; off >>= 1) m = fmaxf(m, __shfl_xor(m, off));
  float ex = __expf(v - m);
  float s = ex;
#pragma unroll
  for (int off = 32; off > 0; off >>= 1) s += __shfl_xor(s, off);
  out[(size_t)node * 64 + lane] = v - m - __logf(s);
}

// ---------------- launch ----------------

extern "C" void kernel_launch(void* const* d_in, const int* in_sizes, int n_in,
                              void* d_out, int out_size, void* d_ws, size_t ws_size,
                              hipStream_t stream) {
  const float* x  = (const float*)d_in[0];
  const int*   ei = (const int*)d_in[1];     // [2, E] int32
  const float* W0 = (const float*)d_in[2];
  const float* b0 = (const float*)d_in[3];
  const float* W1 = (const float*)d_in[4];
  const float* b1 = (const float*)d_in[5];
  const float* W2 = (const float*)d_in[6];
  const float* b2 = (const float*)d_in[7];
  float* outp = (float*)d_out;

  char* p = (char*)d_ws;
  int*   deg    = (int*)p;   p += alup((size_t)N_NODES * 4);
  float* dinv   = (float*)p; p += alup((size_t)N_NODES * 4);
  int*   rowptr = (int*)p;   p += alup((size_t)(N_NODES + 1) * 4);
  int*   cursor = (int*)p;   p += alup((size_t)N_NODES * 4);
  int*   col    = (int*)p;   p += alup((size_t)2 * N_EDGES * 4);
  float* bufA   = (float*)p; p += alup((size_t)N_NODES * 128 * 4);
  float* bufB   = (float*)p;  // N_NODES*128*4 more

  hipMemsetAsync(deg, 0, (size_t)N_NODES * 4, stream);
  k_deg<<<(N_EDGES + 255) / 256, 256, 0, stream>>>(ei, deg);
  k_dinv<<<(N_NODES + 255) / 256, 256, 0, stream>>>(deg, dinv);
  k_scan<<<1, 1024, 0, stream>>>(deg, rowptr, cursor);
  k_scatter<<<(2 * N_EDGES + 255) / 256, 256, 0, stream>>>(ei, cursor, col);

  dim3 g128(640, 2), g64(640, 1);
  // layer 0: gemm -> bufA, agg+relu -> bufB
  k_gemm<128><<<g128, 256, 0, stream>>>(x, W0, bufA);
  k_agg128<true><<<N_NODES / 4, 256, 0, stream>>>(bufA, dinv, rowptr, col, b0, bufB);
  // layer 1
  k_gemm<128><<<g128, 256, 0, stream>>>(bufB, W1, bufA);
  k_agg128<true><<<N_NODES / 4, 256, 0, stream>>>(bufA, dinv, rowptr, col, b1, bufB);
  // layer 2 (width 64) + fused log_softmax
  k_gemm<64><<<g64, 256, 0, stream>>>(bufB, W2, bufA);
  k_agg64_lsm<<<N_NODES / 4, 256, 0, stream>>>(bufA, dinv, rowptr, col, b2, outp);
}

// Round 2
// 1283.632 us; speedup vs baseline: 1.1481x; 1.1481x over previous
//
#include <hip/hip_runtime.h>
#include <hip/hip_bf16.h>
#include <cstdint>

#define N_NODES 100000
#define N_EDGES 1600000
#define NBUK 391   // ceil(N_NODES / 256) buckets of 256 dst nodes
#define CHUNK 4096
#define MAXB 10240 // LDS staging capacity per bucket (mean 8192, +22σ)

static inline size_t alup(size_t x) { return (x + 255) & ~(size_t)255; }

// ---------------- prep kernels ----------------

__global__ __launch_bounds__(256) void k_deg(const int* __restrict__ ei, int* __restrict__ deg) {
  int e = blockIdx.x * 256 + threadIdx.x;
  if (e < N_EDGES) {
    atomicAdd(&deg[ei[e]], 1);            // out node endpoint
    atomicAdd(&deg[ei[N_EDGES + e]], 1);  // in node endpoint
  }
}

__global__ __launch_bounds__(256) void k_dinv(const int* __restrict__ deg, float* __restrict__ dinv) {
  int i = blockIdx.x * 256 + threadIdx.x;
  if (i < N_NODES) dinv[i] = rsqrtf((float)(deg[i] + 1));  // +1 self loop
}

__global__ __launch_bounds__(1024) void k_scan(const int* __restrict__ deg,
                                               int* __restrict__ rowptr) {
  __shared__ int part[1024];
  const int CH = (N_NODES + 1023) / 1024;  // 98
  const int t = threadIdx.x;
  const int s0 = t * CH, s1 = min(s0 + CH, N_NODES);
  int s = 0;
  for (int i = s0; i < s1; ++i) s += deg[i];
  part[t] = s;
  __syncthreads();
  for (int off = 1; off < 1024; off <<= 1) {
    int v = (t >= off) ? part[t - off] : 0;
    __syncthreads();
    if (t >= off) part[t] += v;
    __syncthreads();
  }
  int excl = (t == 0) ? 0 : part[t - 1];
  for (int i = s0; i < s1; ++i) {
    rowptr[i] = excl;
    excl += deg[i];
  }
  if (t == 1023) rowptr[N_NODES] = excl;  // = 2*N_EDGES
}

__global__ __launch_bounds__(256) void k_binit(const int* __restrict__ rowptr,
                                               int* __restrict__ bcursor) {
  int b = blockIdx.x * 256 + threadIdx.x;
  if (b < NBUK) bcursor[b] = rowptr[min(b * 256, N_NODES)];
}

// Pass 1: multisplit edges into 391 coarse dst-buckets with coalesced writes.
// payload pack = (dst&255)<<17 | src   (src < 2^17)
__global__ __launch_bounds__(256) void k_bin(const int* __restrict__ ei,
                                             int* __restrict__ bcursor,
                                             uint32_t* __restrict__ ebuf) {
  __shared__ int hist[NBUK];
  __shared__ int excl[NBUK + 1];
  __shared__ int gbase[NBUK];
  __shared__ uint32_t stage[CHUNK];
  const int tid = threadIdx.x;
  const int base = blockIdx.x * CHUNK;
  const int n = min(CHUNK, 2 * N_EDGES - base);
  for (int i = tid; i < NBUK; i += 256) hist[i] = 0;
  __syncthreads();
  uint32_t pk[16]; int bk[16]; int rk[16];
#pragma unroll
  for (int i = 0; i < 16; ++i) {
    const int li = i * 256 + tid;
    bk[i] = -1;
    if (li < n) {
      const int e = base + li;
      const int src = ei[e];  // src array index is e for both halves
      const int dst = (e < N_EDGES) ? ei[N_EDGES + e] : ei[e - N_EDGES];
      bk[i] = dst >> 8;
      pk[i] = ((uint32_t)(dst & 255) << 17) | (uint32_t)src;
      rk[i] = atomicAdd(&hist[bk[i]], 1);
    }
  }
  __syncthreads();
  if (tid < 64) {  // wave 0: scan 391 counts (7 per lane) + reserve global space
    int c[7]; int s = 0;
#pragma unroll
    for (int j = 0; j < 7; ++j) {
      const int b = tid * 7 + j;
      c[j] = (b < NBUK) ? hist[b] : 0;
      s += c[j];
    }
    int incl = s;
#pragma unroll
    for (int off = 1; off < 64; off <<= 1) {
      const int v = __shfl_up(incl, off);
      if (tid >= off) incl += v;
    }
    int run = incl - s;
#pragma unroll
    for (int j = 0; j < 7; ++j) {
      const int b = tid * 7 + j;
      if (b < NBUK) {
        excl[b] = run;
        gbase[b] = atomicAdd(&bcursor[b], c[j]);
        run += c[j];
      }
    }
    if (tid == 63) excl[NBUK] = incl;
  }
  __syncthreads();
#pragma unroll
  for (int i = 0; i < 16; ++i)
    if (bk[i] >= 0) stage[excl[bk[i]] + rk[i]] = pk[i];
  __syncthreads();
  for (int i = tid; i < n; i += 256) {
    int lo = 0, hi = NBUK - 1;  // largest b with excl[b] <= i
#pragma unroll
    for (int it = 0; it < 9; ++it) {
      const int mid = (lo + hi + 1) >> 1;
      if (excl[mid] <= i) lo = mid; else hi = mid - 1;
    }
    ebuf[gbase[lo] + (i - excl[lo])] = stage[i];  // mostly-sequential bursts
  }
}

// Pass 2: one workgroup per bucket; LDS scatter, coalesced CSR writeback.
__global__ __launch_bounds__(256) void k_csr(const uint32_t* __restrict__ ebuf,
                                             const int* __restrict__ rowptr,
                                             int* __restrict__ col) {
  __shared__ int lcur[256];
  __shared__ int lstage[MAXB];
  const int b = blockIdx.x;
  const int node0 = b << 8;
  const int node1 = min(node0 + 256, N_NODES);
  const int gstart = rowptr[node0];
  const int cnt = rowptr[node1] - gstart;
  const int tid = threadIdx.x;
  lcur[tid] = (node0 + tid < node1) ? (rowptr[node0 + tid] - gstart) : 0;
  __syncthreads();
  for (int i = tid; i < cnt; i += 256) {
    const uint32_t pk = ebuf[gstart + i];
    const int dl = pk >> 17;
    const int src = pk & 0x1FFFF;
    const int p = atomicAdd(&lcur[dl], 1);
    if (p < MAXB) lstage[p] = src;
    else col[gstart + p] = src;  // overflow fallback (statistically never)
  }
  __syncthreads();
  const int m = min(cnt, MAXB);
  for (int i = tid; i < m; i += 256) col[gstart + i] = lstage[i];
}

// ---------------- GEMM: hs = dinv[row] * (x @ W.T)  (fp32) ----------------
template<int OUT>
__global__ __launch_bounds__(256) void k_gemm(const float* __restrict__ x,
                                              const float* __restrict__ W,
                                              const float* __restrict__ dinv,
                                              float* __restrict__ h) {
  __shared__ float wlds[128 * 68];
  __shared__ float xlds[128 * 33];
  const int tid = threadIdx.x;
  const int cg = tid & 15;   // 16 col groups x 4 cols
  const int rg = tid >> 4;   // 16 row groups x 2 rows
  const int obase = blockIdx.y * 64;
  for (int idx = tid; idx < 64 * 32; idx += 256) {
    int o = idx >> 5;
    int k4 = (idx & 31) << 2;
    const float4 wv = *(const float4*)(W + (size_t)(obase + o) * 128 + k4);
    wlds[(k4 + 0) * 68 + o] = wv.x;
    wlds[(k4 + 1) * 68 + o] = wv.y;
    wlds[(k4 + 2) * 68 + o] = wv.z;
    wlds[(k4 + 3) * 68 + o] = wv.w;
  }
  for (int tile = blockIdx.x; tile < N_NODES / 32; tile += gridDim.x) {
    const int row0 = tile * 32;
    __syncthreads();
    for (int idx = tid; idx < 32 * 32; idx += 256) {
      int r = idx >> 5;
      int k4 = (idx & 31) << 2;
      const float4 xv = *(const float4*)(x + (size_t)(row0 + r) * 128 + k4);
      xlds[(k4 + 0) * 33 + r] = xv.x;
      xlds[(k4 + 1) * 33 + r] = xv.y;
      xlds[(k4 + 2) * 33 + r] = xv.z;
      xlds[(k4 + 3) * 33 + r] = xv.w;
    }
    __syncthreads();
    float a00 = 0, a01 = 0, a02 = 0, a03 = 0;
    float a10 = 0, a11 = 0, a12 = 0, a13 = 0;
#pragma unroll 4
    for (int k = 0; k < 128; ++k) {
      const float4 wv = *(const float4*)(wlds + k * 68 + cg * 4);
      const float x0 = xlds[k * 33 + rg * 2 + 0];
      const float x1 = xlds[k * 33 + rg * 2 + 1];
      a00 = fmaf(x0, wv.x, a00); a01 = fmaf(x0, wv.y, a01);
      a02 = fmaf(x0, wv.z, a02); a03 = fmaf(x0, wv.w, a03);
      a10 = fmaf(x1, wv.x, a10); a11 = fmaf(x1, wv.y, a11);
      a12 = fmaf(x1, wv.z, a12); a13 = fmaf(x1, wv.w, a13);
    }
    const float dv0 = dinv[row0 + rg * 2 + 0];
    const float dv1 = dinv[row0 + rg * 2 + 1];
    float* hp = h + (size_t)(row0 + rg * 2) * OUT + obase + cg * 4;
    *(float4*)hp = make_float4(a00 * dv0, a01 * dv0, a02 * dv0, a03 * dv0);
    *(float4*)(hp + OUT) = make_float4(a10 * dv1, a11 * dv1, a12 * dv1, a13 * dv1);
  }
}

// ---------------- aggregation: out[i] = di*(sum_c hs[c] + hs[i]) + b ----------------
template<bool RELU>
__global__ __launch_bounds__(256) void k_agg128(const float* __restrict__ hs,
                                                const float* __restrict__ dinv,
                                                const int* __restrict__ rowptr,
                                                const int* __restrict__ col,
                                                const float* __restrict__ bias,
                                                float* __restrict__ out) {
  const int lane = threadIdx.x & 63;
  const int node = blockIdx.x * 4 + (threadIdx.x >> 6);
  if (node >= N_NODES) return;
  const int e0 = rowptr[node], e1 = rowptr[node + 1];
  const float2* hp = (const float2*)hs;
  const float2 hv = hp[(size_t)node * 64 + lane];  // self loop term (prescaled)
  float ax = hv.x, ay = hv.y;
  for (int eb = e0; eb < e1; eb += 64) {
    const int n = min(64, e1 - eb);
    const int ce = col[min(eb + lane, e1 - 1)];
    for (int j = 0; j < n; ++j) {
      const int c = __shfl(ce, j);
      const float2 v = hp[(size_t)c * 64 + lane];
      ax += v.x;
      ay += v.y;
    }
  }
  const float di = dinv[node];
  const float2 bv = ((const float2*)bias)[lane];
  float ox = di * ax + bv.x;
  float oy = di * ay + bv.y;
  if (RELU) { ox = fmaxf(ox, 0.f); oy = fmaxf(oy, 0.f); }
  ((float2*)out)[(size_t)node * 64 + lane] = make_float2(ox, oy);
}

__global__ __launch_bounds__(256) void k_agg64_lsm(const float* __restrict__ hs,
                                                   const float* __restrict__ dinv,
                                                   const int* __restrict__ rowptr,
                                                   const int* __restrict__ col,
                                                   const float* __restrict__ bias,
                                                   float* __restrict__ out) {
  const int lane = threadIdx.x & 63;
  const int node = blockIdx.x * 4 + (threadIdx.x >> 6);
  if (node >= N_NODES) return;
  const int e0 = rowptr[node], e1 = rowptr[node + 1];
  float acc = hs[(size_t)node * 64 + lane];  // self loop
  for (int eb = e0; eb < e1; eb += 64) {
    const int n = min(64, e1 - eb);
    const int ce = col[min(eb + lane, e1 - 1)];
    for (int j = 0; j < n; ++j) {
      const int c = __shfl(ce, j);
      acc += hs[(size_t)c * 64 + lane];
    }
  }
  const float di = dinv[node];
  float v = di * acc + bias[lane];
  float m = v;
#pragma unroll
  for (int off = 32; off > 0; off >>= 1) m = fmaxf(m, __shfl_xor(m, off));
  float ex = __expf(v - m);
  float s = ex;
#pragma unroll
  for (int off = 32; off > 0; off >>= 1) s += __shfl_xor(s, off);
  out[(size_t)node * 64 + lane] = v - m - __logf(s);
}

// ---------------- launch ----------------

extern "C" void kernel_launch(void* const* d_in, const int* in_sizes, int n_in,
                              void* d_out, int out_size, void* d_ws, size_t ws_size,
                              hipStream_t stream) {
  const float* x  = (const float*)d_in[0];
  const int*   ei = (const int*)d_in[1];
  const float* W0 = (const float*)d_in[2];
  const float* b0 = (const float*)d_in[3];
  const float* W1 = (const float*)d_in[4];
  const float* b1 = (const float*)d_in[5];
  const float* W2 = (const float*)d_in[6];
  const float* b2 = (const float*)d_in[7];
  float* outp = (float*)d_out;

  char* p = (char*)d_ws;
  int*   deg     = (int*)p;   p += alup((size_t)N_NODES * 4);
  float* dinv    = (float*)p; p += alup((size_t)N_NODES * 4);
  int*   rowptr  = (int*)p;   p += alup((size_t)(N_NODES + 1) * 4);
  int*   bcursor = (int*)p;   p += alup((size_t)NBUK * 4);
  int*   col     = (int*)p;   p += alup((size_t)2 * N_EDGES * 4);
  float* bufA    = (float*)p; p += alup((size_t)N_NODES * 128 * 4);
  float* bufB    = (float*)p;
  uint32_t* ebuf = (uint32_t*)bufA;  // pass-1 staging aliases bufA (consumed before gemm0)

  hipMemsetAsync(deg, 0, (size_t)N_NODES * 4, stream);
  k_deg<<<(N_EDGES + 255) / 256, 256, 0, stream>>>(ei, deg);
  k_dinv<<<(N_NODES + 255) / 256, 256, 0, stream>>>(deg, dinv);
  k_scan<<<1, 1024, 0, stream>>>(deg, rowptr);
  k_binit<<<(NBUK + 255) / 256, 256, 0, stream>>>(rowptr, bcursor);
  k_bin<<<(2 * N_EDGES + CHUNK - 1) / CHUNK, 256, 0, stream>>>(ei, bcursor, ebuf);
  k_csr<<<NBUK, 256, 0, stream>>>(ebuf, rowptr, col);

  dim3 g128(640, 2), g64(640, 1);
  k_gemm<128><<<g128, 256, 0, stream>>>(x, W0, dinv, bufA);
  k_agg128<true><<<N_NODES / 4, 256, 0, stream>>>(bufA, dinv, rowptr, col, b0, bufB);
  k_gemm<128><<<g128, 256, 0, stream>>>(bufB, W1, dinv, bufA);
  k_agg128<true><<<N_NODES / 4, 256, 0, stream>>>(bufA, dinv, rowptr, col, b1, bufB);
  k_gemm<64><<<g64, 256, 0, stream>>>(bufB, W2, dinv, bufA);
  k_agg64_lsm<<<N_NODES / 4, 256, 0, stream>>>(bufA, dinv, rowptr, col, b2, outp);
}

// Round 4
// 1193.186 us; speedup vs baseline: 1.2352x; 1.0758x over previous
//
#include <hip/hip_runtime.h>
#include <hip/hip_bf16.h>
#include <cstdint>

#define N_NODES 100000
#define N_EDGES 1600000
#define NBUK 391   // ceil(N_NODES / 256) buckets of 256 dst nodes
#define CHUNK 4096
#define MAXB 10240 // LDS staging capacity per bucket (mean 8192, +22σ)
#define NSB 16     // src super-buckets: src>>13 in [0,13)

static inline size_t alup(size_t x) { return (x + 255) & ~(size_t)255; }

static __device__ __forceinline__ uint32_t pack_bf16x2(float a, float b) {
  uint32_t ua = __float_as_uint(a); ua += 0x7FFF + ((ua >> 16) & 1);
  uint32_t ub = __float_as_uint(b); ub += 0x7FFF + ((ub >> 16) & 1);
  return (ua >> 16) | (ub & 0xFFFF0000u);
}
static __device__ __forceinline__ float bf16lo(uint32_t u) { return __uint_as_float(u << 16); }
static __device__ __forceinline__ float bf16hi(uint32_t u) { return __uint_as_float(u & 0xFFFF0000u); }

// ---------------- prep kernels ----------------

__global__ __launch_bounds__(256) void k_deg(const int* __restrict__ ei, int* __restrict__ deg) {
  int e = blockIdx.x * 256 + threadIdx.x;
  if (e < N_EDGES) {
    atomicAdd(&deg[ei[e]], 1);
    atomicAdd(&deg[ei[N_EDGES + e]], 1);
  }
}

__global__ __launch_bounds__(256) void k_dinv(const int* __restrict__ deg, float* __restrict__ dinv) {
  int i = blockIdx.x * 256 + threadIdx.x;
  if (i < N_NODES) dinv[i] = rsqrtf((float)(deg[i] + 1));  // +1 self loop
}

__global__ __launch_bounds__(1024) void k_scan(const int* __restrict__ deg,
                                               int* __restrict__ rowptr) {
  __shared__ int part[1024];
  const int CH = (N_NODES + 1023) / 1024;  // 98
  const int t = threadIdx.x;
  const int s0 = t * CH, s1 = min(s0 + CH, N_NODES);
  int s = 0;
  for (int i = s0; i < s1; ++i) s += deg[i];
  part[t] = s;
  __syncthreads();
  for (int off = 1; off < 1024; off <<= 1) {
    int v = (t >= off) ? part[t - off] : 0;
    __syncthreads();
    if (t >= off) part[t] += v;
    __syncthreads();
  }
  int excl = (t == 0) ? 0 : part[t - 1];
  for (int i = s0; i < s1; ++i) {
    rowptr[i] = excl;
    excl += deg[i];
  }
  if (t == 1023) rowptr[N_NODES] = excl;  // = 2*N_EDGES
}

__global__ __launch_bounds__(256) void k_binit(const int* __restrict__ rowptr,
                                               int* __restrict__ bcursor) {
  int b = blockIdx.x * 256 + threadIdx.x;
  if (b < NBUK) bcursor[b] = rowptr[min(b * 256, N_NODES)];
}

// Pass 1: multisplit edges into 391 coarse dst-buckets with coalesced writes.
// payload pack = (dst&255)<<17 | src   (src < 2^17)
__global__ __launch_bounds__(256) void k_bin(const int* __restrict__ ei,
                                             int* __restrict__ bcursor,
                                             uint32_t* __restrict__ ebuf) {
  __shared__ int hist[NBUK];
  __shared__ int excl[NBUK + 1];
  __shared__ int gbase[NBUK];
  __shared__ uint32_t stage[CHUNK];
  const int tid = threadIdx.x;
  const int base = blockIdx.x * CHUNK;
  const int n = min(CHUNK, 2 * N_EDGES - base);
  for (int i = tid; i < NBUK; i += 256) hist[i] = 0;
  __syncthreads();
  uint32_t pk[16]; int bk[16]; int rk[16];
#pragma unroll
  for (int i = 0; i < 16; ++i) {
    const int li = i * 256 + tid;
    bk[i] = -1;
    if (li < n) {
      const int e = base + li;
      const int src = ei[e];
      const int dst = (e < N_EDGES) ? ei[N_EDGES + e] : ei[e - N_EDGES];
      bk[i] = dst >> 8;
      pk[i] = ((uint32_t)(dst & 255) << 17) | (uint32_t)src;
      rk[i] = atomicAdd(&hist[bk[i]], 1);
    }
  }
  __syncthreads();
  if (tid < 64) {
    int c[7]; int s = 0;
#pragma unroll
    for (int j = 0; j < 7; ++j) {
      const int b = tid * 7 + j;
      c[j] = (b < NBUK) ? hist[b] : 0;
      s += c[j];
    }
    int incl = s;
#pragma unroll
    for (int off = 1; off < 64; off <<= 1) {
      const int v = __shfl_up(incl, off);
      if (tid >= off) incl += v;
    }
    int run = incl - s;
#pragma unroll
    for (int j = 0; j < 7; ++j) {
      const int b = tid * 7 + j;
      if (b < NBUK) {
        excl[b] = run;
        gbase[b] = atomicAdd(&bcursor[b], c[j]);
        run += c[j];
      }
    }
    if (tid == 63) excl[NBUK] = incl;
  }
  __syncthreads();
#pragma unroll
  for (int i = 0; i < 16; ++i)
    if (bk[i] >= 0) stage[excl[bk[i]] + rk[i]] = pk[i];
  __syncthreads();
  for (int i = tid; i < n; i += 256) {
    int lo = 0, hi = NBUK - 1;
#pragma unroll
    for (int it = 0; it < 9; ++it) {
      const int mid = (lo + hi + 1) >> 1;
      if (excl[mid] <= i) lo = mid; else hi = mid - 1;
    }
    ebuf[gbase[lo] + (i - excl[lo])] = stage[i];
  }
}

// Pass 2: one workgroup per bucket. Counting sort by (dst_local, src>>13) so each
// node's neighbor list is grouped by src super-bucket (L2-locality sync across waves),
// then coalesced CSR writeback.
__global__ __launch_bounds__(256) void k_csr(const uint32_t* __restrict__ ebuf,
                                             const int* __restrict__ rowptr,
                                             int* __restrict__ col) {
  __shared__ int cnt[256 * NSB];   // 16 KB
  __shared__ int lstage[MAXB];     // 40 KB
  const int b = blockIdx.x;
  const int node0 = b << 8;
  const int node1 = min(node0 + 256, N_NODES);
  const int gstart = rowptr[node0];
  const int total = rowptr[node1] - gstart;
  const int tid = threadIdx.x;
  for (int i = tid; i < 256 * NSB; i += 256) cnt[i] = 0;
  __syncthreads();
  for (int i = tid; i < total; i += 256) {
    const uint32_t pk = ebuf[gstart + i];
    atomicAdd(&cnt[(pk >> 17) * NSB + ((pk & 0x1FFFF) >> 13)], 1);
  }
  __syncthreads();
  {  // per-segment scan: thread dl owns its 16 counters
    const int dl = tid;
    int run = (node0 + dl < node1) ? (rowptr[node0 + dl] - gstart) : 0;
#pragma unroll
    for (int s = 0; s < NSB; ++s) {
      const int c = cnt[dl * NSB + s];
      cnt[dl * NSB + s] = run;
      run += c;
    }
  }
  __syncthreads();
  for (int i = tid; i < total; i += 256) {
    const uint32_t pk = ebuf[gstart + i];
    const int src = pk & 0x1FFFF;
    const int p = atomicAdd(&cnt[(pk >> 17) * NSB + (src >> 13)], 1);
    if (p < MAXB) lstage[p] = src;
    else col[gstart + p] = src;  // overflow fallback (statistically never)
  }
  __syncthreads();
  const int m = min(total, MAXB);
  for (int i = tid; i < m; i += 256) col[gstart + i] = lstage[i];
}

// ---------------- GEMM: hs = dinv[row] * (x @ W.T) ----------------
// BF16OUT: pack pairs of columns into uint32 bf16x2 (halves gather bytes downstream).
template<int OUT, bool BF16OUT>
__global__ __launch_bounds__(256) void k_gemm(const float* __restrict__ x,
                                              const float* __restrict__ W,
                                              const float* __restrict__ dinv,
                                              void* __restrict__ hout) {
  __shared__ float wlds[128 * 68];
  __shared__ float xlds[128 * 33];
  const int tid = threadIdx.x;
  const int cg = tid & 15;
  const int rg = tid >> 4;
  const int obase = blockIdx.y * 64;
  for (int idx = tid; idx < 64 * 32; idx += 256) {
    int o = idx >> 5;
    int k4 = (idx & 31) << 2;
    const float4 wv = *(const float4*)(W + (size_t)(obase + o) * 128 + k4);
    wlds[(k4 + 0) * 68 + o] = wv.x;
    wlds[(k4 + 1) * 68 + o] = wv.y;
    wlds[(k4 + 2) * 68 + o] = wv.z;
    wlds[(k4 + 3) * 68 + o] = wv.w;
  }
  for (int tile = blockIdx.x; tile < N_NODES / 32; tile += gridDim.x) {
    const int row0 = tile * 32;
    __syncthreads();
    for (int idx = tid; idx < 32 * 32; idx += 256) {
      int r = idx >> 5;
      int k4 = (idx & 31) << 2;
      const float4 xv = *(const float4*)(x + (size_t)(row0 + r) * 128 + k4);
      xlds[(k4 + 0) * 33 + r] = xv.x;
      xlds[(k4 + 1) * 33 + r] = xv.y;
      xlds[(k4 + 2) * 33 + r] = xv.z;
      xlds[(k4 + 3) * 33 + r] = xv.w;
    }
    __syncthreads();
    float a00 = 0, a01 = 0, a02 = 0, a03 = 0;
    float a10 = 0, a11 = 0, a12 = 0, a13 = 0;
#pragma unroll 4
    for (int k = 0; k < 128; ++k) {
      const float4 wv = *(const float4*)(wlds + k * 68 + cg * 4);
      const float x0 = xlds[k * 33 + rg * 2 + 0];
      const float x1 = xlds[k * 33 + rg * 2 + 1];
      a00 = fmaf(x0, wv.x, a00); a01 = fmaf(x0, wv.y, a01);
      a02 = fmaf(x0, wv.z, a02); a03 = fmaf(x0, wv.w, a03);
      a10 = fmaf(x1, wv.x, a10); a11 = fmaf(x1, wv.y, a11);
      a12 = fmaf(x1, wv.z, a12); a13 = fmaf(x1, wv.w, a13);
    }
    const float dv0 = dinv[row0 + rg * 2 + 0];
    const float dv1 = dinv[row0 + rg * 2 + 1];
    if (BF16OUT) {
      // column-pair index = obase/2 + cg*2  (this offset was missing in round 3)
      uint32_t* hp = (uint32_t*)hout + (size_t)(row0 + rg * 2) * (OUT / 2) + obase / 2 + cg * 2;
      *(uint2*)hp = make_uint2(pack_bf16x2(a00 * dv0, a01 * dv0), pack_bf16x2(a02 * dv0, a03 * dv0));
      *(uint2*)(hp + OUT / 2) = make_uint2(pack_bf16x2(a10 * dv1, a11 * dv1), pack_bf16x2(a12 * dv1, a13 * dv1));
    } else {
      float* hp = (float*)hout + (size_t)(row0 + rg * 2) * OUT + obase + cg * 4;
      *(float4*)hp = make_float4(a00 * dv0, a01 * dv0, a02 * dv0, a03 * dv0);
      *(float4*)(hp + OUT) = make_float4(a10 * dv1, a11 * dv1, a12 * dv1, a13 * dv1);
    }
  }
}

// ---------------- aggregation (bf16 gather): out[i] = di*(sum_c hs[c] + hs[i]) + b ----------------
// One wave per node; lane holds packed cols {2l,2l+1}; fp32 accumulation.
template<bool RELU>
__global__ __launch_bounds__(256) void k_agg128(const uint32_t* __restrict__ hs,
                                                const float* __restrict__ dinv,
                                                const int* __restrict__ rowptr,
                                                const int* __restrict__ col,
                                                const float* __restrict__ bias,
                                                float* __restrict__ out) {
  const int lane = threadIdx.x & 63;
  const int node = blockIdx.x * 4 + (threadIdx.x >> 6);
  if (node >= N_NODES) return;
  const int e0 = rowptr[node], e1 = rowptr[node + 1];
  const uint32_t us = hs[(size_t)node * 64 + lane];  // prescaled self-loop term
  float ax = bf16lo(us), ay = bf16hi(us);
  for (int eb = e0; eb < e1; eb += 64) {
    const int n = min(64, e1 - eb);
    const int ce = col[min(eb + lane, e1 - 1)];
#pragma unroll 4
    for (int j = 0; j < n; ++j) {
      const int c = __shfl(ce, j);
      const uint32_t u = hs[(size_t)c * 64 + lane];
      ax += bf16lo(u);
      ay += bf16hi(u);
    }
  }
  const float di = dinv[node];
  const float2 bv = ((const float2*)bias)[lane];
  float ox = di * ax + bv.x;
  float oy = di * ay + bv.y;
  if (RELU) { ox = fmaxf(ox, 0.f); oy = fmaxf(oy, 0.f); }
  ((float2*)out)[(size_t)node * 64 + lane] = make_float2(ox, oy);
}

// Final layer: fp32 gather (accuracy), fused bias + log_softmax.
__global__ __launch_bounds__(256) void k_agg64_lsm(const float* __restrict__ hs,
                                                   const float* __restrict__ dinv,
                                                   const int* __restrict__ rowptr,
                                                   const int* __restrict__ col,
                                                   const float* __restrict__ bias,
                                                   float* __restrict__ out) {
  const int lane = threadIdx.x & 63;
  const int node = blockIdx.x * 4 + (threadIdx.x >> 6);
  if (node >= N_NODES) return;
  const int e0 = rowptr[node], e1 = rowptr[node + 1];
  float acc = hs[(size_t)node * 64 + lane];
  for (int eb = e0; eb < e1; eb += 64) {
    const int n = min(64, e1 - eb);
    const int ce = col[min(eb + lane, e1 - 1)];
#pragma unroll 4
    for (int j = 0; j < n; ++j) {
      const int c = __shfl(ce, j);
      acc += hs[(size_t)c * 64 + lane];
    }
  }
  const float di = dinv[node];
  float v = di * acc + bias[lane];
  float m = v;
#pragma unroll
  for (int off = 32; off > 0; off >>= 1) m = fmaxf(m, __shfl_xor(m, off));
  float ex = __expf(v - m);
  float s = ex;
#pragma unroll
  for (int off = 32; off > 0; off >>= 1) s += __shfl_xor(s, off);
  out[(size_t)node * 64 + lane] = v - m - __logf(s);
}

// ---------------- launch ----------------

extern "C" void kernel_launch(void* const* d_in, const int* in_sizes, int n_in,
                              void* d_out, int out_size, void* d_ws, size_t ws_size,
                              hipStream_t stream) {
  const float* x  = (const float*)d_in[0];
  const int*   ei = (const int*)d_in[1];
  const float* W0 = (const float*)d_in[2];
  const float* b0 = (const float*)d_in[3];
  const float* W1 = (const float*)d_in[4];
  const float* b1 = (const float*)d_in[5];
  const float* W2 = (const float*)d_in[6];
  const float* b2 = (const float*)d_in[7];
  float* outp = (float*)d_out;

  char* p = (char*)d_ws;
  int*   deg     = (int*)p;   p += alup((size_t)N_NODES * 4);
  float* dinv    = (float*)p; p += alup((size_t)N_NODES * 4);
  int*   rowptr  = (int*)p;   p += alup((size_t)(N_NODES + 1) * 4);
  int*   bcursor = (int*)p;   p += alup((size_t)NBUK * 4);
  int*   col     = (int*)p;   p += alup((size_t)2 * N_EDGES * 4);
  float* bufA    = (float*)p; p += alup((size_t)N_NODES * 128 * 4);
  float* bufB    = (float*)p;
  uint32_t* ebuf = (uint32_t*)bufA;       // pass-1 staging aliases bufA
  uint32_t* h16  = (uint32_t*)bufA;       // bf16x2 gemm output (layers 0/1)

  hipMemsetAsync(deg, 0, (size_t)N_NODES * 4, stream);
  k_deg<<<(N_EDGES + 255) / 256, 256, 0, stream>>>(ei, deg);
  k_dinv<<<(N_NODES + 255) / 256, 256, 0, stream>>>(deg, dinv);
  k_scan<<<1, 1024, 0, stream>>>(deg, rowptr);
  k_binit<<<(NBUK + 255) / 256, 256, 0, stream>>>(rowptr, bcursor);
  k_bin<<<(2 * N_EDGES + CHUNK - 1) / CHUNK, 256, 0, stream>>>(ei, bcursor, ebuf);
  k_csr<<<NBUK, 256, 0, stream>>>(ebuf, rowptr, col);

  dim3 g128(640, 2), g64(640, 1);
  k_gemm<128, true><<<g128, 256, 0, stream>>>(x, W0, dinv, h16);
  k_agg128<true><<<N_NODES / 4, 256, 0, stream>>>(h16, dinv, rowptr, col, b0, bufB);
  k_gemm<128, true><<<g128, 256, 0, stream>>>(bufB, W1, dinv, h16);
  k_agg128<true><<<N_NODES / 4, 256, 0, stream>>>(h16, dinv, rowptr, col, b1, bufB);
  k_gemm<64, false><<<g64, 256, 0, stream>>>(bufB, W2, dinv, bufA);
  k_agg64_lsm<<<N_NODES / 4, 256, 0, stream>>>(bufA, dinv, rowptr, col, b2, outp);
}

// Round 5
// 1117.851 us; speedup vs baseline: 1.3184x; 1.0674x over previous
//
#include <hip/hip_runtime.h>
#include <hip/hip_bf16.h>
#include <cstdint>

#define N_NODES 100000
#define N_EDGES 1600000
#define NBUK 391   // ceil(N_NODES / 256) buckets of 256 dst nodes
#define CHUNK 4096
#define MAXB 10240 // LDS staging capacity per bucket (mean 8192, +22σ)
#define NSB 16     // src super-buckets: src>>13 in [0,13)

static inline size_t alup(size_t x) { return (x + 255) & ~(size_t)255; }

static __device__ __forceinline__ uint32_t pack_bf16x2(float a, float b) {
  uint32_t ua = __float_as_uint(a); ua += 0x7FFF + ((ua >> 16) & 1);
  uint32_t ub = __float_as_uint(b); ub += 0x7FFF + ((ub >> 16) & 1);
  return (ua >> 16) | (ub & 0xFFFF0000u);
}
static __device__ __forceinline__ float bf16lo(uint32_t u) { return __uint_as_float(u << 16); }
static __device__ __forceinline__ float bf16hi(uint32_t u) { return __uint_as_float(u & 0xFFFF0000u); }

// ---------------- prep kernels ----------------

__global__ __launch_bounds__(256) void k_deg(const int* __restrict__ ei, int* __restrict__ deg) {
  int e = blockIdx.x * 256 + threadIdx.x;
  if (e < N_EDGES) {
    atomicAdd(&deg[ei[e]], 1);
    atomicAdd(&deg[ei[N_EDGES + e]], 1);
  }
}

__global__ __launch_bounds__(256) void k_dinv(const int* __restrict__ deg, float* __restrict__ dinv) {
  int i = blockIdx.x * 256 + threadIdx.x;
  if (i < N_NODES) dinv[i] = rsqrtf((float)(deg[i] + 1));  // +1 self loop
}

__global__ __launch_bounds__(1024) void k_scan(const int* __restrict__ deg,
                                               int* __restrict__ rowptr) {
  __shared__ int part[1024];
  const int CH = (N_NODES + 1023) / 1024;  // 98
  const int t = threadIdx.x;
  const int s0 = t * CH, s1 = min(s0 + CH, N_NODES);
  int s = 0;
  for (int i = s0; i < s1; ++i) s += deg[i];
  part[t] = s;
  __syncthreads();
  for (int off = 1; off < 1024; off <<= 1) {
    int v = (t >= off) ? part[t - off] : 0;
    __syncthreads();
    if (t >= off) part[t] += v;
    __syncthreads();
  }
  int excl = (t == 0) ? 0 : part[t - 1];
  for (int i = s0; i < s1; ++i) {
    rowptr[i] = excl;
    excl += deg[i];
  }
  if (t == 1023) rowptr[N_NODES] = excl;  // = 2*N_EDGES
}

__global__ __launch_bounds__(256) void k_binit(const int* __restrict__ rowptr,
                                               int* __restrict__ bcursor) {
  int b = blockIdx.x * 256 + threadIdx.x;
  if (b < NBUK) bcursor[b] = rowptr[min(b * 256, N_NODES)];
}

// Pass 1: multisplit edges into 391 coarse dst-buckets with coalesced writes.
// payload pack = (dst&255)<<17 | src   (src < 2^17)
__global__ __launch_bounds__(256) void k_bin(const int* __restrict__ ei,
                                             int* __restrict__ bcursor,
                                             uint32_t* __restrict__ ebuf) {
  __shared__ int hist[NBUK];
  __shared__ int excl[NBUK + 1];
  __shared__ int gbase[NBUK];
  __shared__ uint32_t stage[CHUNK];
  const int tid = threadIdx.x;
  const int base = blockIdx.x * CHUNK;
  const int n = min(CHUNK, 2 * N_EDGES - base);
  for (int i = tid; i < NBUK; i += 256) hist[i] = 0;
  __syncthreads();
  uint32_t pk[16]; int bk[16]; int rk[16];
#pragma unroll
  for (int i = 0; i < 16; ++i) {
    const int li = i * 256 + tid;
    bk[i] = -1;
    if (li < n) {
      const int e = base + li;
      const int src = ei[e];
      const int dst = (e < N_EDGES) ? ei[N_EDGES + e] : ei[e - N_EDGES];
      bk[i] = dst >> 8;
      pk[i] = ((uint32_t)(dst & 255) << 17) | (uint32_t)src;
      rk[i] = atomicAdd(&hist[bk[i]], 1);
    }
  }
  __syncthreads();
  if (tid < 64) {
    int c[7]; int s = 0;
#pragma unroll
    for (int j = 0; j < 7; ++j) {
      const int b = tid * 7 + j;
      c[j] = (b < NBUK) ? hist[b] : 0;
      s += c[j];
    }
    int incl = s;
#pragma unroll
    for (int off = 1; off < 64; off <<= 1) {
      const int v = __shfl_up(incl, off);
      if (tid >= off) incl += v;
    }
    int run = incl - s;
#pragma unroll
    for (int j = 0; j < 7; ++j) {
      const int b = tid * 7 + j;
      if (b < NBUK) {
        excl[b] = run;
        gbase[b] = atomicAdd(&bcursor[b], c[j]);
        run += c[j];
      }
    }
    if (tid == 63) excl[NBUK] = incl;
  }
  __syncthreads();
#pragma unroll
  for (int i = 0; i < 16; ++i)
    if (bk[i] >= 0) stage[excl[bk[i]] + rk[i]] = pk[i];
  __syncthreads();
  for (int i = tid; i < n; i += 256) {
    int lo = 0, hi = NBUK - 1;
#pragma unroll
    for (int it = 0; it < 9; ++it) {
      const int mid = (lo + hi + 1) >> 1;
      if (excl[mid] <= i) lo = mid; else hi = mid - 1;
    }
    ebuf[gbase[lo] + (i - excl[lo])] = stage[i];
  }
}

// Pass 2: one workgroup per bucket. Counting sort by (dst_local, src>>13) so each
// node's neighbor list is grouped by src super-bucket (L2-locality sync across waves),
// then coalesced CSR writeback.
__global__ __launch_bounds__(256) void k_csr(const uint32_t* __restrict__ ebuf,
                                             const int* __restrict__ rowptr,
                                             int* __restrict__ col) {
  __shared__ int cnt[256 * NSB];   // 16 KB
  __shared__ int lstage[MAXB];     // 40 KB
  const int b = blockIdx.x;
  const int node0 = b << 8;
  const int node1 = min(node0 + 256, N_NODES);
  const int gstart = rowptr[node0];
  const int total = rowptr[node1] - gstart;
  const int tid = threadIdx.x;
  for (int i = tid; i < 256 * NSB; i += 256) cnt[i] = 0;
  __syncthreads();
  for (int i = tid; i < total; i += 256) {
    const uint32_t pk = ebuf[gstart + i];
    atomicAdd(&cnt[(pk >> 17) * NSB + ((pk & 0x1FFFF) >> 13)], 1);
  }
  __syncthreads();
  {  // per-segment scan: thread dl owns its 16 counters
    const int dl = tid;
    int run = (node0 + dl < node1) ? (rowptr[node0 + dl] - gstart) : 0;
#pragma unroll
    for (int s = 0; s < NSB; ++s) {
      const int c = cnt[dl * NSB + s];
      cnt[dl * NSB + s] = run;
      run += c;
    }
  }
  __syncthreads();
  for (int i = tid; i < total; i += 256) {
    const uint32_t pk = ebuf[gstart + i];
    const int src = pk & 0x1FFFF;
    const int p = atomicAdd(&cnt[(pk >> 17) * NSB + (src >> 13)], 1);
    if (p < MAXB) lstage[p] = src;
    else col[gstart + p] = src;  // overflow fallback (statistically never)
  }
  __syncthreads();
  const int m = min(total, MAXB);
  for (int i = tid; i < m; i += 256) col[gstart + i] = lstage[i];
}

// ---------------- GEMM: hs = dinv[row] * (x @ W.T) ----------------
// BF16OUT: pack pairs of columns into uint32 bf16x2 (halves gather bytes downstream).
template<int OUT, bool BF16OUT>
__global__ __launch_bounds__(256) void k_gemm(const float* __restrict__ x,
                                              const float* __restrict__ W,
                                              const float* __restrict__ dinv,
                                              void* __restrict__ hout) {
  __shared__ float wlds[128 * 68];
  __shared__ float xlds[128 * 33];
  const int tid = threadIdx.x;
  const int cg = tid & 15;
  const int rg = tid >> 4;
  const int obase = blockIdx.y * 64;
  for (int idx = tid; idx < 64 * 32; idx += 256) {
    int o = idx >> 5;
    int k4 = (idx & 31) << 2;
    const float4 wv = *(const float4*)(W + (size_t)(obase + o) * 128 + k4);
    wlds[(k4 + 0) * 68 + o] = wv.x;
    wlds[(k4 + 1) * 68 + o] = wv.y;
    wlds[(k4 + 2) * 68 + o] = wv.z;
    wlds[(k4 + 3) * 68 + o] = wv.w;
  }
  for (int tile = blockIdx.x; tile < N_NODES / 32; tile += gridDim.x) {
    const int row0 = tile * 32;
    __syncthreads();
    for (int idx = tid; idx < 32 * 32; idx += 256) {
      int r = idx >> 5;
      int k4 = (idx & 31) << 2;
      const float4 xv = *(const float4*)(x + (size_t)(row0 + r) * 128 + k4);
      xlds[(k4 + 0) * 33 + r] = xv.x;
      xlds[(k4 + 1) * 33 + r] = xv.y;
      xlds[(k4 + 2) * 33 + r] = xv.z;
      xlds[(k4 + 3) * 33 + r] = xv.w;
    }
    __syncthreads();
    float a00 = 0, a01 = 0, a02 = 0, a03 = 0;
    float a10 = 0, a11 = 0, a12 = 0, a13 = 0;
#pragma unroll 4
    for (int k = 0; k < 128; ++k) {
      const float4 wv = *(const float4*)(wlds + k * 68 + cg * 4);
      const float x0 = xlds[k * 33 + rg * 2 + 0];
      const float x1 = xlds[k * 33 + rg * 2 + 1];
      a00 = fmaf(x0, wv.x, a00); a01 = fmaf(x0, wv.y, a01);
      a02 = fmaf(x0, wv.z, a02); a03 = fmaf(x0, wv.w, a03);
      a10 = fmaf(x1, wv.x, a10); a11 = fmaf(x1, wv.y, a11);
      a12 = fmaf(x1, wv.z, a12); a13 = fmaf(x1, wv.w, a13);
    }
    const float dv0 = dinv[row0 + rg * 2 + 0];
    const float dv1 = dinv[row0 + rg * 2 + 1];
    if (BF16OUT) {
      uint32_t* hp = (uint32_t*)hout + (size_t)(row0 + rg * 2) * (OUT / 2) + obase / 2 + cg * 2;
      *(uint2*)hp = make_uint2(pack_bf16x2(a00 * dv0, a01 * dv0), pack_bf16x2(a02 * dv0, a03 * dv0));
      *(uint2*)(hp + OUT / 2) = make_uint2(pack_bf16x2(a10 * dv1, a11 * dv1), pack_bf16x2(a12 * dv1, a13 * dv1));
    } else {
      float* hp = (float*)hout + (size_t)(row0 + rg * 2) * OUT + obase + cg * 4;
      *(float4*)hp = make_float4(a00 * dv0, a01 * dv0, a02 * dv0, a03 * dv0);
      *(float4*)(hp + OUT) = make_float4(a10 * dv1, a11 * dv1, a12 * dv1, a13 * dv1);
    }
  }
}

// ---------------- aggregation (bf16 gather): out[i] = di*(sum_c hs[c] + hs[i]) + b ----------------
// One wave per node; lane holds packed cols {2l,2l+1}; fp32 accumulation.
template<bool RELU>
__global__ __launch_bounds__(256) void k_agg128(const uint32_t* __restrict__ hs,
                                                const float* __restrict__ dinv,
                                                const int* __restrict__ rowptr,
                                                const int* __restrict__ col,
                                                const float* __restrict__ bias,
                                                float* __restrict__ out) {
  const int lane = threadIdx.x & 63;
  const int node = blockIdx.x * 4 + (threadIdx.x >> 6);
  if (node >= N_NODES) return;
  const int e0 = rowptr[node], e1 = rowptr[node + 1];
  const uint32_t us = hs[(size_t)node * 64 + lane];  // prescaled self-loop term
  float ax = bf16lo(us), ay = bf16hi(us);
  for (int eb = e0; eb < e1; eb += 64) {
    const int n = min(64, e1 - eb);
    const int ce = col[min(eb + lane, e1 - 1)];
#pragma unroll 4
    for (int j = 0; j < n; ++j) {
      const int c = __shfl(ce, j);
      const uint32_t u = hs[(size_t)c * 64 + lane];
      ax += bf16lo(u);
      ay += bf16hi(u);
    }
  }
  const float di = dinv[node];
  const float2 bv = ((const float2*)bias)[lane];
  float ox = di * ax + bv.x;
  float oy = di * ay + bv.y;
  if (RELU) { ox = fmaxf(ox, 0.f); oy = fmaxf(oy, 0.f); }
  ((float2*)out)[(size_t)node * 64 + lane] = make_float2(ox, oy);
}

// Final layer: bf16 gather (row = 32 u32 words), paired-edge wave layout.
// Lanes 0-31 handle even edges, 32-63 odd edges; combine via shfl_xor(32).
// Fused bias + log_softmax (2 cols/lane over 32 lanes).
__global__ __launch_bounds__(256) void k_agg64_lsm(const uint32_t* __restrict__ hs,
                                                   const float* __restrict__ dinv,
                                                   const int* __restrict__ rowptr,
                                                   const int* __restrict__ col,
                                                   const float* __restrict__ bias,
                                                   float* __restrict__ out) {
  const int lane = threadIdx.x & 63;
  const int half = lane >> 5;   // 0 = even edges, 1 = odd edges
  const int w = lane & 31;      // word index: cols {2w, 2w+1}
  const int node = blockIdx.x * 4 + (threadIdx.x >> 6);
  if (node >= N_NODES) return;
  const int e0 = rowptr[node], e1 = rowptr[node + 1];
  float ax = 0.f, ay = 0.f;
  if (half == 0) {  // self-loop term counted once
    const uint32_t us = hs[(size_t)node * 32 + w];
    ax = bf16lo(us); ay = bf16hi(us);
  }
  for (int eb = e0; eb < e1; eb += 64) {
    const int n = min(64, e1 - eb);
    const int ce = col[min(eb + lane, e1 - 1)];
    const int hn = (n + 1) >> 1;
    for (int j = 0; j < hn; ++j) {
      const int idx = 2 * j + half;
      const int c = __shfl(ce, idx);
      if (idx < n) {
        const uint32_t u = hs[(size_t)c * 32 + w];
        ax += bf16lo(u);
        ay += bf16hi(u);
      }
    }
  }
  ax += __shfl_xor(ax, 32);
  ay += __shfl_xor(ay, 32);
  const float di = dinv[node];
  const float2 bv = ((const float2*)bias)[w];
  const float v0 = di * ax + bv.x;
  const float v1 = di * ay + bv.y;
  float m = fmaxf(v0, v1);
#pragma unroll
  for (int off = 16; off > 0; off >>= 1) m = fmaxf(m, __shfl_xor(m, off));
  float s = __expf(v0 - m) + __expf(v1 - m);
#pragma unroll
  for (int off = 16; off > 0; off >>= 1) s += __shfl_xor(s, off);
  const float ls = m + __logf(s);
  if (half == 0)
    ((float2*)out)[(size_t)node * 32 + w] = make_float2(v0 - ls, v1 - ls);
}

// ---------------- launch ----------------

extern "C" void kernel_launch(void* const* d_in, const int* in_sizes, int n_in,
                              void* d_out, int out_size, void* d_ws, size_t ws_size,
                              hipStream_t stream) {
  const float* x  = (const float*)d_in[0];
  const int*   ei = (const int*)d_in[1];
  const float* W0 = (const float*)d_in[2];
  const float* b0 = (const float*)d_in[3];
  const float* W1 = (const float*)d_in[4];
  const float* b1 = (const float*)d_in[5];
  const float* W2 = (const float*)d_in[6];
  const float* b2 = (const float*)d_in[7];
  float* outp = (float*)d_out;

  char* p = (char*)d_ws;
  int*   deg     = (int*)p;   p += alup((size_t)N_NODES * 4);
  float* dinv    = (float*)p; p += alup((size_t)N_NODES * 4);
  int*   rowptr  = (int*)p;   p += alup((size_t)(N_NODES + 1) * 4);
  int*   bcursor = (int*)p;   p += alup((size_t)NBUK * 4);
  int*   col     = (int*)p;   p += alup((size_t)2 * N_EDGES * 4);
  float* bufA    = (float*)p; p += alup((size_t)N_NODES * 128 * 4);
  float* bufB    = (float*)p;
  uint32_t* ebuf = (uint32_t*)bufA;       // pass-1 staging aliases bufA
  uint32_t* h16  = (uint32_t*)bufA;       // bf16x2 gemm output (all layers)

  hipMemsetAsync(deg, 0, (size_t)N_NODES * 4, stream);
  k_deg<<<(N_EDGES + 255) / 256, 256, 0, stream>>>(ei, deg);
  k_dinv<<<(N_NODES + 255) / 256, 256, 0, stream>>>(deg, dinv);
  k_scan<<<1, 1024, 0, stream>>>(deg, rowptr);
  k_binit<<<(NBUK + 255) / 256, 256, 0, stream>>>(rowptr, bcursor);
  k_bin<<<(2 * N_EDGES + CHUNK - 1) / CHUNK, 256, 0, stream>>>(ei, bcursor, ebuf);
  k_csr<<<NBUK, 256, 0, stream>>>(ebuf, rowptr, col);

  dim3 g128(640, 2), g64(640, 1);
  k_gemm<128, true><<<g128, 256, 0, stream>>>(x, W0, dinv, h16);
  k_agg128<true><<<N_NODES / 4, 256, 0, stream>>>(h16, dinv, rowptr, col, b0, bufB);
  k_gemm<128, true><<<g128, 256, 0, stream>>>(bufB, W1, dinv, h16);
  k_agg128<true><<<N_NODES / 4, 256, 0, stream>>>(h16, dinv, rowptr, col, b1, bufB);
  k_gemm<64, true><<<g64, 256, 0, stream>>>(bufB, W2, dinv, h16);
  k_agg64_lsm<<<N_NODES / 4, 256, 0, stream>>>(h16, dinv, rowptr, col, b2, outp);
}